// Round 1
// baseline (6512.529 us; speedup 1.0000x reference)
//
#include <hip/hip_runtime.h>
#include <math.h>

// ---------------- problem constants ----------------
constexpr int B_  = 2;
constexpr int S_  = 2048;
constexpr int V_  = 32000;
constexpr int E_  = 512;
constexpr int H_  = 8;
constexpr int L_  = 4;
constexpr int DH_ = 64;     // E/H
constexpr int M_  = 256;    // FAVOR features
constexpr int CH_ = 128;    // chunk
constexpr int NC_ = 16;     // S/CH
constexpr int NTOK_ = B_ * S_;   // 4096

// ---------------- wave helpers ----------------
__device__ __forceinline__ float warp_sum64(float x) {
#pragma unroll
  for (int off = 32; off; off >>= 1) x += __shfl_xor(x, off);
  return x;
}
__device__ __forceinline__ float warp_max64(float x) {
#pragma unroll
  for (int off = 32; off; off >>= 1) x = fmaxf(x, __shfl_xor(x, off));
  return x;
}

// ---------------- embed + posenc + LN ----------------
__global__ __launch_bounds__(256) void embed_ln_k(
    const int* __restrict__ src, const float* __restrict__ emb,
    const float* __restrict__ g, const float* __restrict__ bta,
    float* __restrict__ X) {
  __shared__ float red[4];
  const int row = blockIdx.x;          // b*S + s
  const int s   = row & (S_ - 1);
  const int tid = threadIdx.x;
  const int tok = src[row];
  float v[2];
#pragma unroll
  for (int i = 0; i < 2; i++) {
    const int e = tid + i * 256;
    const float j = (float)(e & ~1);
    const float div = expf(j * (-9.210340371976184f / (float)E_)); // ln(1e4)
    const float ang = (float)s * div;
    const float pe = (e & 1) ? cosf(ang) : sinf(ang);
    v[i] = emb[(size_t)tok * E_ + e] + pe;
  }
  float sum = warp_sum64(v[0] + v[1]);
  if ((tid & 63) == 0) red[tid >> 6] = sum;
  __syncthreads();
  const float mu = (red[0] + red[1] + red[2] + red[3]) * (1.f / E_);
  __syncthreads();
  const float d0 = v[0] - mu, d1 = v[1] - mu;
  float s2 = warp_sum64(d0 * d0 + d1 * d1);
  if ((tid & 63) == 0) red[tid >> 6] = s2;
  __syncthreads();
  const float var = (red[0] + red[1] + red[2] + red[3]) * (1.f / E_);
  const float r = rsqrtf(var + 1e-5f);
  X[(size_t)row * E_ + tid]       = d0 * r * g[tid] + bta[tid];
  X[(size_t)row * E_ + tid + 256] = d1 * r * g[tid + 256] + bta[tid + 256];
}

// ---------------- generic row LayerNorm ----------------
__global__ __launch_bounds__(256) void ln_rows_k(
    const float* __restrict__ Xin, const float* __restrict__ g,
    const float* __restrict__ bta, float* __restrict__ Y) {
  __shared__ float red[4];
  const int row = blockIdx.x, tid = threadIdx.x;
  const float* xr = Xin + (size_t)row * E_;
  const float v0 = xr[tid], v1 = xr[tid + 256];
  float sum = warp_sum64(v0 + v1);
  if ((tid & 63) == 0) red[tid >> 6] = sum;
  __syncthreads();
  const float mu = (red[0] + red[1] + red[2] + red[3]) * (1.f / E_);
  __syncthreads();
  const float d0 = v0 - mu, d1 = v1 - mu;
  float s2 = warp_sum64(d0 * d0 + d1 * d1);
  if ((tid & 63) == 0) red[tid >> 6] = s2;
  __syncthreads();
  const float var = (red[0] + red[1] + red[2] + red[3]) * (1.f / E_);
  const float r = rsqrtf(var + 1e-5f);
  Y[(size_t)row * E_ + tid]       = d0 * r * g[tid] + bta[tid];
  Y[(size_t)row * E_ + tid + 256] = d1 * r * g[tid + 256] + bta[tid + 256];
}

// ---------------- fp32 tiled GEMM: C = A[MrxKd] @ B[KdxNc] (+bias)(+gelu)(+=C) ----------------
template <bool BIAS, bool ACC, bool GACT>
__global__ __launch_bounds__(256) void gemm_f32(
    const float* __restrict__ A, const float* __restrict__ Bm,
    const float* __restrict__ bias, float* __restrict__ C,
    int Mr, int Nc, int Kd) {
  constexpr int BM = 128, BN = 128, BK = 16;
  __shared__ alignas(16) float As[BK][BM + 4];  // [k][m], 132 stride: 16B aligned rows
  __shared__ alignas(16) float Bs[BK][BN];
  const int tid = threadIdx.x;
  const int bm = blockIdx.y * BM, bn = blockIdx.x * BN;
  const int tr = tid >> 4, tc = tid & 15;
  float acc[8][8];
#pragma unroll
  for (int i = 0; i < 8; i++)
#pragma unroll
    for (int j = 0; j < 8; j++) acc[i][j] = 0.f;
  const int arow = tid >> 2;          // 0..63
  const int acol = (tid & 3) * 4;     // 0,4,8,12
  const int brow = tid >> 5;          // 0..7
  const int bcol = (tid & 31) * 4;    // 0..124
  for (int k0 = 0; k0 < Kd; k0 += BK) {
#pragma unroll
    for (int half = 0; half < 2; half++) {
      const float4 av = *reinterpret_cast<const float4*>(
          &A[(size_t)(bm + arow + half * 64) * Kd + k0 + acol]);
      As[acol + 0][arow + half * 64] = av.x;
      As[acol + 1][arow + half * 64] = av.y;
      As[acol + 2][arow + half * 64] = av.z;
      As[acol + 3][arow + half * 64] = av.w;
      const float4 bv = *reinterpret_cast<const float4*>(
          &Bm[(size_t)(k0 + brow + half * 8) * Nc + bn + bcol]);
      *reinterpret_cast<float4*>(&Bs[brow + half * 8][bcol]) = bv;
    }
    __syncthreads();
#pragma unroll
    for (int kk = 0; kk < BK; kk++) {
      float a[8], b[8];
      *reinterpret_cast<float4*>(&a[0]) = *reinterpret_cast<const float4*>(&As[kk][tr * 8]);
      *reinterpret_cast<float4*>(&a[4]) = *reinterpret_cast<const float4*>(&As[kk][tr * 8 + 4]);
      *reinterpret_cast<float4*>(&b[0]) = *reinterpret_cast<const float4*>(&Bs[kk][tc * 8]);
      *reinterpret_cast<float4*>(&b[4]) = *reinterpret_cast<const float4*>(&Bs[kk][tc * 8 + 4]);
#pragma unroll
      for (int i = 0; i < 8; i++)
#pragma unroll
        for (int j = 0; j < 8; j++) acc[i][j] += a[i] * b[j];
    }
    __syncthreads();
  }
#pragma unroll
  for (int i = 0; i < 8; i++) {
    const size_t r = bm + tr * 8 + i;
#pragma unroll
    for (int j = 0; j < 8; j++) {
      const int cc = bn + tc * 8 + j;
      const size_t cidx = r * (size_t)Nc + cc;
      float v = acc[i][j];
      if constexpr (BIAS) v += bias[cc];
      if constexpr (GACT) v = 0.5f * v * (1.f + erff(v * 0.7071067811865475f));
      if constexpr (ACC) v += C[cidx];
      C[cidx] = v;
    }
  }
}

// ---------------- FAVOR+ query features ----------------
__global__ __launch_bounds__(256) void feat_q_k(
    const float* __restrict__ Q, const float* __restrict__ P,
    float* __restrict__ QF) {
  __shared__ alignas(16) float qrow[64];
  __shared__ float red[4];
  const int tid = threadIdx.x, bx = blockIdx.x;
  const int st = bx & 255, h = (bx >> 8) & 7, b = bx >> 11;
  float4 preg[16];
#pragma unroll
  for (int i = 0; i < 16; i++)
    preg[i] = *reinterpret_cast<const float4*>(&P[(size_t)tid * DH_ + i * 4]);
  const float dn = 0.35355339059327373f;  // 64^-0.25
  for (int ss = 0; ss < 8; ss++) {
    const int s = st * 8 + ss;
    if (tid < 64) qrow[tid] = Q[((size_t)(b * S_ + s)) * E_ + h * DH_ + tid];
    __syncthreads();
    float xd = 0.f, q2 = 0.f;
#pragma unroll
    for (int i = 0; i < 16; i++) {
      const float4 q4 = *reinterpret_cast<const float4*>(&qrow[i * 4]);
      xd += preg[i].x * q4.x + preg[i].y * q4.y + preg[i].z * q4.z + preg[i].w * q4.w;
      q2 += q4.x * q4.x + q4.y * q4.y + q4.z * q4.z + q4.w * q4.w;
    }
    xd *= dn;
    const float dg = 0.5f * dn * dn * q2;
    float mx = warp_max64(xd);
    if ((tid & 63) == 0) red[tid >> 6] = mx;
    __syncthreads();
    mx = fmaxf(fmaxf(red[0], red[1]), fmaxf(red[2], red[3]));
    QF[(((size_t)(b * H_ + h)) * S_ + s) * M_ + tid] =
        0.0625f * (expf(xd - dg - mx) + 1e-4f);
    __syncthreads();
  }
}

// ---------------- FAVOR+ key features: phase 1 (xd + diag + block max) ----------------
__global__ __launch_bounds__(256) void feat_k1_k(
    const float* __restrict__ K, const float* __restrict__ P,
    float* __restrict__ KF, float* __restrict__ DIAGK, float* __restrict__ PMAX) {
  __shared__ alignas(16) float krow[64];
  __shared__ float red[4];
  const int tid = threadIdx.x, bx = blockIdx.x;
  const int st = bx & 255, h = (bx >> 8) & 7, b = bx >> 11;
  float4 preg[16];
#pragma unroll
  for (int i = 0; i < 16; i++)
    preg[i] = *reinterpret_cast<const float4*>(&P[(size_t)tid * DH_ + i * 4]);
  const float dn = 0.35355339059327373f;
  float bmax = -3.0e38f;
  for (int ss = 0; ss < 8; ss++) {
    const int s = st * 8 + ss;
    if (tid < 64) krow[tid] = K[((size_t)(b * S_ + s)) * E_ + h * DH_ + tid];
    __syncthreads();
    float xd = 0.f, q2 = 0.f;
#pragma unroll
    for (int i = 0; i < 16; i++) {
      const float4 q4 = *reinterpret_cast<const float4*>(&krow[i * 4]);
      xd += preg[i].x * q4.x + preg[i].y * q4.y + preg[i].z * q4.z + preg[i].w * q4.w;
      q2 += q4.x * q4.x + q4.y * q4.y + q4.z * q4.z + q4.w * q4.w;
    }
    xd *= dn;
    const float dg = 0.5f * dn * dn * q2;
    const size_t ridx = ((size_t)(b * H_ + h)) * S_ + s;
    KF[ridx * M_ + tid] = xd;
    if (tid == 0) DIAGK[ridx] = dg;
    bmax = fmaxf(bmax, xd);
    __syncthreads();
  }
  bmax = warp_max64(bmax);
  if ((tid & 63) == 0) red[tid >> 6] = bmax;
  __syncthreads();
  if (tid == 0) PMAX[bx] = fmaxf(fmaxf(red[0], red[1]), fmaxf(red[2], red[3]));
}

// ---------------- global max reduce ----------------
__global__ __launch_bounds__(256) void maxred_k(
    const float* __restrict__ PM, int n, float* __restrict__ G) {
  __shared__ float w[4];
  const int tid = threadIdx.x;
  float v = -3.0e38f;
  for (int i = tid; i < n; i += 256) v = fmaxf(v, PM[i]);
  v = warp_max64(v);
  if ((tid & 63) == 0) w[tid >> 6] = v;
  __syncthreads();
  if (tid == 0) G[0] = fmaxf(fmaxf(w[0], w[1]), fmaxf(w[2], w[3]));
}

// ---------------- key features: phase 2 (exp transform in place) ----------------
__global__ __launch_bounds__(256) void feat_k2_k(
    float* __restrict__ KF, const float* __restrict__ DIAG,
    const float* __restrict__ G) {
  const float gm = G[0];
  const size_t n = (size_t)B_ * H_ * S_ * M_;
  for (size_t i = (size_t)blockIdx.x * 256 + threadIdx.x; i < n;
       i += (size_t)gridDim.x * 256) {
    const float xd = KF[i];
    const float dg = DIAG[i >> 8];  // M_=256
    KF[i] = 0.0625f * (expf(xd - dg - gm) + 1e-4f);
  }
}

// ---------------- per-chunk k^T v sums ----------------
__global__ __launch_bounds__(256) void chunk_sums_k(
    const float* __restrict__ KF, const float* __restrict__ V,
    float* __restrict__ CSKV, float* __restrict__ CSZ) {
  __shared__ alignas(16) float vl[CH_ * DH_];  // 32 KB
  const int tid = threadIdx.x, blk = blockIdx.x;
  const int c = blk & 15, h = (blk >> 4) & 7, b = blk >> 7;
  const int bh = b * H_ + h;
#pragma unroll
  for (int i = 0; i < 32; i++) {
    const int e = i * 256 + tid;
    vl[e] = V[((size_t)(b * S_ + c * CH_ + (e >> 6))) * E_ + h * DH_ + (e & 63)];
  }
  __syncthreads();
  float4 acc[16];
#pragma unroll
  for (int i = 0; i < 16; i++) acc[i] = make_float4(0.f, 0.f, 0.f, 0.f);
  float z = 0.f;
  const size_t kfbase = ((size_t)bh * S_ + c * CH_) * M_ + tid;
  for (int t = 0; t < CH_; t++) {
    const float kf = KF[kfbase + (size_t)t * M_];
    z += kf;
#pragma unroll
    for (int i = 0; i < 16; i++) {
      const float4 vv = *reinterpret_cast<const float4*>(&vl[t * DH_ + i * 4]);
      acc[i].x += kf * vv.x; acc[i].y += kf * vv.y;
      acc[i].z += kf * vv.z; acc[i].w += kf * vv.w;
    }
  }
  const size_t base = ((size_t)bh * NC_ + c) * (M_ * DH_) + (size_t)tid * DH_;
#pragma unroll
  for (int i = 0; i < 16; i++)
    *reinterpret_cast<float4*>(&CSKV[base + i * 4]) = acc[i];
  CSZ[((size_t)bh * NC_ + c) * M_ + tid] = z;
}

// ---------------- exclusive prefix over chunks (in place) ----------------
__global__ __launch_bounds__(256) void chunk_prefix_k(
    float* __restrict__ CSKV, float* __restrict__ CSZ) {
  const int tid = threadIdx.x, bx = blockIdx.x;
  const int ds = bx & 15, bh = bx >> 4;
  float run[4] = {0.f, 0.f, 0.f, 0.f};
  for (int c = 0; c < NC_; c++) {
    const size_t base = ((size_t)bh * NC_ + c) * (M_ * DH_) + ds * 1024;
#pragma unroll
    for (int i = 0; i < 4; i++) {
      const size_t idx = base + i * 256 + tid;
      const float t = CSKV[idx];
      CSKV[idx] = run[i];
      run[i] += t;
    }
  }
  if (ds == 0) {
    float zr = 0.f;
    for (int c = 0; c < NC_; c++) {
      const size_t idx = ((size_t)bh * NC_ + c) * M_ + tid;
      const float t = CSZ[idx];
      CSZ[idx] = zr;
      zr += t;
    }
  }
}

// ---------------- in-chunk inclusive recurrence -> attention output ----------------
// One block per (b,h,chunk,d-half). State 256 x 32 in LDS (stride 36, conflict-free).
__global__ __launch_bounds__(256) void attn_out_k(
    const float* __restrict__ QF, const float* __restrict__ KF,
    const float* __restrict__ V, const float* __restrict__ CSKV,
    const float* __restrict__ CSZ, float* __restrict__ O) {
  constexpr int DSP = 32;
  __shared__ alignas(16) float Sl[M_ * 36];
  __shared__ alignas(16) float qrow[M_];
  __shared__ alignas(16) float vrow[DSP];
  __shared__ float np[256];
  __shared__ float denp[4];
  const int tid = threadIdx.x, blk = blockIdx.x;
  const int dh = blk & 1, c = (blk >> 1) & 15, h = (blk >> 5) & 7, b = blk >> 8;
  const int bh = b * H_ + h;
  const size_t sbase = ((size_t)bh * NC_ + c) * (M_ * DH_) + dh * DSP;
#pragma unroll
  for (int i = 0; i < 32; i++) {
    const int e = i * 256 + tid;  // 8192: m=e>>5, d=e&31
    Sl[(e >> 5) * 36 + (e & 31)] = CSKV[sbase + (size_t)(e >> 5) * DH_ + (e & 31)];
  }
  float zreg = CSZ[((size_t)bh * NC_ + c) * M_ + tid];
  const int wid = tid >> 6, lane = tid & 63;
  __syncthreads();
  const size_t qkbase = ((size_t)bh * S_ + c * CH_) * M_;
  for (int t = 0; t < CH_; t++) {
    const int sg = c * CH_ + t;
    if (tid < DSP) vrow[tid] = V[((size_t)(b * S_ + sg)) * E_ + h * DH_ + dh * DSP + tid];
    qrow[tid] = QF[qkbase + (size_t)t * M_ + tid];
    const float kft = KF[qkbase + (size_t)t * M_ + tid];
    __syncthreads();  // #1: staging done
    zreg += kft;
    float* srow = &Sl[tid * 36];
#pragma unroll
    for (int i = 0; i < 8; i++) {
      float4 sv = *reinterpret_cast<float4*>(&srow[i * 4]);
      const float4 vv = *reinterpret_cast<const float4*>(&vrow[i * 4]);
      sv.x += kft * vv.x; sv.y += kft * vv.y;
      sv.z += kft * vv.z; sv.w += kft * vv.w;
      *reinterpret_cast<float4*>(&srow[i * 4]) = sv;
    }
    const float dp = warp_sum64(qrow[tid] * zreg);
    if (lane == 0) denp[wid] = dp;
    __syncthreads();  // #2: state updated, denp written
    {
      const int g = tid >> 5, d = tid & 31;
      float p = 0.f;
#pragma unroll
      for (int mm = 0; mm < 32; mm++)
        p += qrow[g * 32 + mm] * Sl[(g * 32 + mm) * 36 + d];
      np[g * 32 + d] = p;
    }
    __syncthreads();  // #3: partials written
    if (tid < DSP) {
      float num = 0.f;
#pragma unroll
      for (int g = 0; g < 8; g++) num += np[g * 32 + tid];
      const float den = denp[0] + denp[1] + denp[2] + denp[3];
      O[((size_t)(b * S_ + sg)) * E_ + h * DH_ + dh * DSP + tid] =
          num / (den + 1e-6f);
    }
  }
}

// ---------------- host launch ----------------
extern "C" void kernel_launch(void* const* d_in, const int* in_sizes, int n_in,
                              void* d_out, int out_size, void* d_ws, size_t ws_size,
                              hipStream_t stream) {
  const int*   src      = (const int*)d_in[0];
  // d_in[1] = tgt (dead in reference)
  const float* emb      = (const float*)d_in[2];
  const float* ln_emb_g = (const float*)d_in[3];
  const float* ln_emb_b = (const float*)d_in[4];
  const float* Wq       = (const float*)d_in[5];
  const float* Wk       = (const float*)d_in[6];
  const float* Wv       = (const float*)d_in[7];
  const float* Wo       = (const float*)d_in[8];
  const float* ln1_g    = (const float*)d_in[9];
  const float* ln1_b    = (const float*)d_in[10];
  const float* W1       = (const float*)d_in[11];
  const float* b1       = (const float*)d_in[12];
  const float* W2       = (const float*)d_in[13];
  const float* b2       = (const float*)d_in[14];
  const float* ln2_g    = (const float*)d_in[15];
  const float* ln2_b    = (const float*)d_in[16];
  const float* proj     = (const float*)d_in[17];
  const float* fc_w     = (const float*)d_in[18];
  const float* fc_b     = (const float*)d_in[19];
  float* out = (float*)d_out;
  float* ws  = (float*)d_ws;

  size_t off = 0;
  auto alloc = [&](size_t n) {
    float* p = ws + off;
    off += (n + 63) & ~(size_t)63;
    return p;
  };
  float* X    = alloc((size_t)NTOK_ * E_);
  float* Hb   = alloc((size_t)NTOK_ * E_);
  float* Qb   = alloc((size_t)NTOK_ * E_);   // also attention output O
  float* Kb   = alloc((size_t)NTOK_ * E_);
  float* Vb   = alloc((size_t)NTOK_ * E_);
  float* QF   = alloc((size_t)B_ * H_ * S_ * M_);  // also FFN intermediate (same size)
  float* KF   = alloc((size_t)B_ * H_ * S_ * M_);
  float* CSKV = alloc((size_t)B_ * H_ * NC_ * M_ * DH_);
  float* CSZ  = alloc((size_t)B_ * H_ * NC_ * M_);
  float* DIAGK= alloc((size_t)B_ * H_ * S_);
  float* PMAX = alloc(4096);
  float* GMAX = alloc(64);

  const dim3 blk256(256);
  const dim3 gE(E_ / 128, NTOK_ / 128);        // (4, 32)
  const dim3 g4E(4 * E_ / 128, NTOK_ / 128);   // (16, 32)
  const dim3 gV(V_ / 128, NTOK_ / 128);        // (250, 32)

  embed_ln_k<<<NTOK_, blk256, 0, stream>>>(src, emb, ln_emb_g, ln_emb_b, X);

  for (int l = 0; l < L_; l++) {
    const float* Pl = proj + (size_t)l * M_ * DH_;
    ln_rows_k<<<NTOK_, blk256, 0, stream>>>(X, ln1_g + l * E_, ln1_b + l * E_, Hb);
    gemm_f32<false, false, false><<<gE, blk256, 0, stream>>>(
        Hb, Wq + (size_t)l * E_ * E_, nullptr, Qb, NTOK_, E_, E_);
    gemm_f32<false, false, false><<<gE, blk256, 0, stream>>>(
        Hb, Wk + (size_t)l * E_ * E_, nullptr, Kb, NTOK_, E_, E_);
    gemm_f32<false, false, false><<<gE, blk256, 0, stream>>>(
        Hb, Wv + (size_t)l * E_ * E_, nullptr, Vb, NTOK_, E_, E_);
    feat_q_k<<<B_ * H_ * (S_ / 8), blk256, 0, stream>>>(Qb, Pl, QF);
    feat_k1_k<<<B_ * H_ * (S_ / 8), blk256, 0, stream>>>(Kb, Pl, KF, DIAGK, PMAX);
    maxred_k<<<1, blk256, 0, stream>>>(PMAX, B_ * H_ * (S_ / 8), GMAX);
    feat_k2_k<<<4096, blk256, 0, stream>>>(KF, DIAGK, GMAX);
    chunk_sums_k<<<B_ * H_ * NC_, blk256, 0, stream>>>(KF, Vb, CSKV, CSZ);
    chunk_prefix_k<<<B_ * H_ * 16, blk256, 0, stream>>>(CSKV, CSZ);
    attn_out_k<<<B_ * H_ * NC_ * 2, blk256, 0, stream>>>(QF, KF, Vb, CSKV, CSZ, Qb);
    gemm_f32<false, true, false><<<gE, blk256, 0, stream>>>(
        Qb, Wo + (size_t)l * E_ * E_, nullptr, X, NTOK_, E_, E_);
    ln_rows_k<<<NTOK_, blk256, 0, stream>>>(X, ln2_g + l * E_, ln2_b + l * E_, Hb);
    gemm_f32<true, false, true><<<g4E, blk256, 0, stream>>>(
        Hb, W1 + (size_t)l * E_ * 4 * E_, b1 + (size_t)l * 4 * E_, QF, NTOK_, 4 * E_, E_);
    gemm_f32<true, true, false><<<gE, blk256, 0, stream>>>(
        QF, W2 + (size_t)l * 4 * E_ * E_, b2 + (size_t)l * E_, X, NTOK_, E_, 4 * E_);
  }
  gemm_f32<true, false, false><<<gV, blk256, 0, stream>>>(
      X, fc_w, fc_b, out, NTOK_, V_, E_);
}

// Round 2
// 4125.199 us; speedup vs baseline: 1.5787x; 1.5787x over previous
//
#include <hip/hip_runtime.h>
#include <math.h>

typedef unsigned short u16;
typedef unsigned int u32;
typedef __attribute__((ext_vector_type(8))) short bf16x8;
typedef __attribute__((ext_vector_type(4))) float f32x4;

// ---------------- problem constants ----------------
constexpr int B_  = 2;
constexpr int S_  = 2048;
constexpr int V_  = 32000;
constexpr int E_  = 512;
constexpr int H_  = 8;
constexpr int L_  = 4;
constexpr int DH_ = 64;     // E/H
constexpr int M_  = 256;    // FAVOR features
constexpr int CH_ = 128;    // chunk
constexpr int NC_ = 16;     // S/CH
constexpr int NTOK_ = B_ * S_;   // 4096
constexpr int KE_ = 3 * E_;      // 1536 extended-K for K=512
constexpr int KF_ = 3 * 4 * E_;  // 6144 extended-K for K=2048

// ---------------- helpers ----------------
__device__ __forceinline__ float warp_sum64(float x) {
#pragma unroll
  for (int off = 32; off; off >>= 1) x += __shfl_xor(x, off);
  return x;
}
__device__ __forceinline__ float warp_max64(float x) {
#pragma unroll
  for (int off = 32; off; off >>= 1) x = fmaxf(x, __shfl_xor(x, off));
  return x;
}
__device__ __forceinline__ u16 bf16_rne(float x) {
  u32 u = __builtin_bit_cast(u32, x);
  u += 0x7fffu + ((u >> 16) & 1u);
  return (u16)(u >> 16);
}
__device__ __forceinline__ float bf16_f(u16 h) {
  u32 u = ((u32)h) << 16;
  return __builtin_bit_cast(float, u);
}
__device__ __forceinline__ void gload_lds16(const u16* g, u16* l) {
  __builtin_amdgcn_global_load_lds(
      (const __attribute__((address_space(1))) void*)g,
      (__attribute__((address_space(3))) void*)l, 16, 0, 0);
}
// write one fp32 value as [hi | hi | lo] ext triplet at row base (stride seg)
__device__ __forceinline__ void ext_write(u16* ro, int col, int seg, float v) {
  const u16 hi = bf16_rne(v);
  const u16 lo = bf16_rne(v - bf16_f(hi));
  ro[col] = hi; ro[seg + col] = hi; ro[2 * seg + col] = lo;
}

// ---------------- embed + posenc + LN ----------------
__global__ __launch_bounds__(256) void embed_ln_k(
    const int* __restrict__ src, const float* __restrict__ emb,
    const float* __restrict__ g, const float* __restrict__ bta,
    float* __restrict__ X) {
  __shared__ float red[4];
  const int row = blockIdx.x;          // b*S + s
  const int s   = row & (S_ - 1);
  const int tid = threadIdx.x;
  const int tok = src[row];
  float v[2];
#pragma unroll
  for (int i = 0; i < 2; i++) {
    const int e = tid + i * 256;
    const float j = (float)(e & ~1);
    const float div = expf(j * (-9.210340371976184f / (float)E_)); // ln(1e4)
    const float ang = (float)s * div;
    const float pe = (e & 1) ? cosf(ang) : sinf(ang);
    v[i] = emb[(size_t)tok * E_ + e] + pe;
  }
  float sum = warp_sum64(v[0] + v[1]);
  if ((tid & 63) == 0) red[tid >> 6] = sum;
  __syncthreads();
  const float mu = (red[0] + red[1] + red[2] + red[3]) * (1.f / E_);
  __syncthreads();
  const float d0 = v[0] - mu, d1 = v[1] - mu;
  float s2 = warp_sum64(d0 * d0 + d1 * d1);
  if ((tid & 63) == 0) red[tid >> 6] = s2;
  __syncthreads();
  const float var = (red[0] + red[1] + red[2] + red[3]) * (1.f / E_);
  const float r = rsqrtf(var + 1e-5f);
  X[(size_t)row * E_ + tid]       = d0 * r * g[tid] + bta[tid];
  X[(size_t)row * E_ + tid + 256] = d1 * r * g[tid + 256] + bta[tid + 256];
}

// ---------------- row LayerNorm -> ext bf16 (GEMM-A format) ----------------
__global__ __launch_bounds__(256) void ln_rows_ext_k(
    const float* __restrict__ Xin, const float* __restrict__ g,
    const float* __restrict__ bta, u16* __restrict__ Eo) {
  __shared__ float red[4];
  const int row = blockIdx.x, tid = threadIdx.x;
  const float* xr = Xin + (size_t)row * E_;
  const float v0 = xr[tid], v1 = xr[tid + 256];
  float sum = warp_sum64(v0 + v1);
  if ((tid & 63) == 0) red[tid >> 6] = sum;
  __syncthreads();
  const float mu = (red[0] + red[1] + red[2] + red[3]) * (1.f / E_);
  __syncthreads();
  const float d0 = v0 - mu, d1 = v1 - mu;
  float s2 = warp_sum64(d0 * d0 + d1 * d1);
  if ((tid & 63) == 0) red[tid >> 6] = s2;
  __syncthreads();
  const float var = (red[0] + red[1] + red[2] + red[3]) * (1.f / E_);
  const float r = rsqrtf(var + 1e-5f);
  u16* ro = Eo + (size_t)row * KE_;
  ext_write(ro, tid,       E_, d0 * r * g[tid] + bta[tid]);
  ext_write(ro, tid + 256, E_, d1 * r * g[tid + 256] + bta[tid + 256]);
}

// ---------------- X fp32 -> ext bf16 ----------------
__global__ __launch_bounds__(256) void xconv_k(
    const float* __restrict__ X, u16* __restrict__ Eo) {
  const int row = blockIdx.x, tid = threadIdx.x;
  u16* ro = Eo + (size_t)row * KE_;
#pragma unroll
  for (int i = 0; i < 2; i++) {
    const int e = tid + i * 256;
    ext_write(ro, e, E_, X[(size_t)row * E_ + e]);
  }
}

// ---------------- weight convert: W[K][N] fp32 -> D[N][3K] bf16 [hi|lo|hi] ----------------
__global__ __launch_bounds__(256) void convw_k(
    const float* __restrict__ W, u16* __restrict__ D, int K, int ldsrc) {
  __shared__ float t[32][33];
  const int tid = threadIdx.x;
  const int n0 = blockIdx.x * 32, k0 = blockIdx.y * 32;
  const int r = tid >> 5, c = tid & 31;
#pragma unroll
  for (int i = 0; i < 4; i++)
    t[r + i * 8][c] = W[(size_t)(k0 + r + i * 8) * ldsrc + n0 + c];
  __syncthreads();
#pragma unroll
  for (int i = 0; i < 4; i++) {
    const int nn = r + i * 8;
    const float v = t[c][nn];
    const u16 hi = bf16_rne(v);
    const u16 lo = bf16_rne(v - bf16_f(hi));
    u16* ro = D + (size_t)(n0 + nn) * (3 * K) + k0 + c;
    ro[0] = hi; ro[K] = lo; ro[2 * K] = hi;
  }
}

// 4 square E x E weights at once (Q,K,V,O), selected by blockIdx.z
__global__ __launch_bounds__(256) void convw4_k(
    const float* __restrict__ p0, const float* __restrict__ p1,
    const float* __restrict__ p2, const float* __restrict__ p3,
    u16* __restrict__ D) {
  __shared__ float t[32][33];
  const int tid = threadIdx.x, z = blockIdx.z;
  const float* ps[4] = {p0, p1, p2, p3};
  const float* W = ps[z];
  u16* Dz = D + (size_t)z * E_ * KE_;
  const int n0 = blockIdx.x * 32, k0 = blockIdx.y * 32;
  const int r = tid >> 5, c = tid & 31;
#pragma unroll
  for (int i = 0; i < 4; i++)
    t[r + i * 8][c] = W[(size_t)(k0 + r + i * 8) * E_ + n0 + c];
  __syncthreads();
#pragma unroll
  for (int i = 0; i < 4; i++) {
    const int nn = r + i * 8;
    const float v = t[c][nn];
    const u16 hi = bf16_rne(v);
    const u16 lo = bf16_rne(v - bf16_f(hi));
    u16* ro = Dz + (size_t)(n0 + nn) * KE_ + k0 + c;
    ro[0] = hi; ro[E_] = lo; ro[2 * E_] = hi;
  }
}

// ---------------- bf16x3 MFMA GEMM ----------------
// C[M][N](f32) = A_ext[M][Kp](bf16) . Bt_ext[N][Kp](bf16)^T   (extended-K fp32 emulation)
// BM=128: 4 waves as 2x2, wave tile 64x64.  BM=64: 4 waves as 1x4, wave tile 64x32.
template <int BM, bool BIAS, bool ACC, bool GEXT>
__global__ __launch_bounds__(256) void gemm_bf3(
    const u16* __restrict__ A, const u16* __restrict__ Bt,
    const float* __restrict__ bias, float* __restrict__ C,
    u16* __restrict__ Eo, int Kp, int ldC, int NE) {
  constexpr int BN = 128, BK = 64;
  constexpr int WROWS = BM / 64;       // 2 or 1
  constexpr int WCOLS = 4 / WROWS;     // 2 or 4
  constexpr int CW = BN / WCOLS;       // 64 or 32
  constexpr int MR = 4;
  constexpr int NR = CW / 16;          // 4 or 2
  __shared__ u16 Al[BM * BK];
  __shared__ u16 Bl[BN * BK];
  const int tid = threadIdx.x;
  const int wid = tid >> 6, lane = tid & 63;
  const int wr = wid / WCOLS, wc = wid % WCOLS;
  const int l15 = lane & 15, l4 = lane >> 4;
  const int bm = blockIdx.y * BM, bn = blockIdx.x * BN;
  f32x4 acc[MR][NR];
#pragma unroll
  for (int i = 0; i < MR; i++)
#pragma unroll
    for (int j = 0; j < NR; j++) acc[i][j] = (f32x4)(0.f);
  const int srow = tid >> 3;          // 0..31
  const int scol = (tid & 7) * 8;     // 0..56
  const u16* Abase = A + (size_t)(bm + srow) * Kp + scol;
  const u16* Bbase = Bt + (size_t)(bn + srow) * Kp + scol;
  for (int k0 = 0; k0 < Kp; k0 += BK) {
#pragma unroll
    for (int i = 0; i < BM / 32; i++)
      gload_lds16(Abase + (size_t)(i * 32) * Kp + k0, Al + i * 2048 + tid * 8);
#pragma unroll
    for (int i = 0; i < 4; i++)
      gload_lds16(Bbase + (size_t)(i * 32) * Kp + k0, Bl + i * 2048 + tid * 8);
    __syncthreads();
#pragma unroll
    for (int kk = 0; kk < BK; kk += 32) {
      bf16x8 af[MR], bfr[NR];
#pragma unroll
      for (int i = 0; i < MR; i++)
        af[i] = *reinterpret_cast<const bf16x8*>(
            &Al[(wr * 64 + i * 16 + l15) * BK + kk + l4 * 8]);
#pragma unroll
      for (int j = 0; j < NR; j++)
        bfr[j] = *reinterpret_cast<const bf16x8*>(
            &Bl[(wc * CW + j * 16 + l15) * BK + kk + l4 * 8]);
#pragma unroll
      for (int i = 0; i < MR; i++)
#pragma unroll
        for (int j = 0; j < NR; j++)
          acc[i][j] = __builtin_amdgcn_mfma_f32_16x16x32_bf16(
              af[i], bfr[j], acc[i][j], 0, 0, 0);
    }
    __syncthreads();
  }
  // epilogue: C/D layout col=lane&15, row=(lane>>4)*4+reg
#pragma unroll
  for (int i = 0; i < MR; i++) {
#pragma unroll
    for (int j = 0; j < NR; j++) {
#pragma unroll
      for (int r = 0; r < 4; r++) {
        const int row = bm + wr * 64 + i * 16 + l4 * 4 + r;
        const int col = bn + wc * CW + j * 16 + l15;
        float v = acc[i][j][r];
        if constexpr (BIAS) v += bias[col];
        if constexpr (GEXT) {
          v = 0.5f * v * (1.f + erff(v * 0.7071067811865475f));
          ext_write(Eo + (size_t)row * (3 * NE), col, NE, v);
        } else {
          const size_t ci = (size_t)row * ldC + col;
          if constexpr (ACC) C[ci] += v; else C[ci] = v;
        }
      }
    }
  }
}

// ---------------- FAVOR+ query features ----------------
__global__ __launch_bounds__(256) void feat_q_k(
    const float* __restrict__ Q, const float* __restrict__ P,
    float* __restrict__ QF) {
  __shared__ alignas(16) float qrow[64];
  __shared__ float red[4];
  const int tid = threadIdx.x, bx = blockIdx.x;
  const int st = bx & 255, h = (bx >> 8) & 7, b = bx >> 11;
  float4 preg[16];
#pragma unroll
  for (int i = 0; i < 16; i++)
    preg[i] = *reinterpret_cast<const float4*>(&P[(size_t)tid * DH_ + i * 4]);
  const float dn = 0.35355339059327373f;  // 64^-0.25
  for (int ss = 0; ss < 8; ss++) {
    const int s = st * 8 + ss;
    if (tid < 64) qrow[tid] = Q[((size_t)(b * S_ + s)) * E_ + h * DH_ + tid];
    __syncthreads();
    float xd = 0.f, q2 = 0.f;
#pragma unroll
    for (int i = 0; i < 16; i++) {
      const float4 q4 = *reinterpret_cast<const float4*>(&qrow[i * 4]);
      xd += preg[i].x * q4.x + preg[i].y * q4.y + preg[i].z * q4.z + preg[i].w * q4.w;
      q2 += q4.x * q4.x + q4.y * q4.y + q4.z * q4.z + q4.w * q4.w;
    }
    xd *= dn;
    const float dg = 0.5f * dn * dn * q2;
    float mx = warp_max64(xd);
    if ((tid & 63) == 0) red[tid >> 6] = mx;
    __syncthreads();
    mx = fmaxf(fmaxf(red[0], red[1]), fmaxf(red[2], red[3]));
    QF[(((size_t)(b * H_ + h)) * S_ + s) * M_ + tid] =
        0.0625f * (expf(xd - dg - mx) + 1e-4f);
    __syncthreads();
  }
}

// ---------------- FAVOR+ key features: phase 1 ----------------
__global__ __launch_bounds__(256) void feat_k1_k(
    const float* __restrict__ K, const float* __restrict__ P,
    float* __restrict__ KF, float* __restrict__ DIAGK, float* __restrict__ PMAX) {
  __shared__ alignas(16) float krow[64];
  __shared__ float red[4];
  const int tid = threadIdx.x, bx = blockIdx.x;
  const int st = bx & 255, h = (bx >> 8) & 7, b = bx >> 11;
  float4 preg[16];
#pragma unroll
  for (int i = 0; i < 16; i++)
    preg[i] = *reinterpret_cast<const float4*>(&P[(size_t)tid * DH_ + i * 4]);
  const float dn = 0.35355339059327373f;
  float bmax = -3.0e38f;
  for (int ss = 0; ss < 8; ss++) {
    const int s = st * 8 + ss;
    if (tid < 64) krow[tid] = K[((size_t)(b * S_ + s)) * E_ + h * DH_ + tid];
    __syncthreads();
    float xd = 0.f, q2 = 0.f;
#pragma unroll
    for (int i = 0; i < 16; i++) {
      const float4 q4 = *reinterpret_cast<const float4*>(&krow[i * 4]);
      xd += preg[i].x * q4.x + preg[i].y * q4.y + preg[i].z * q4.z + preg[i].w * q4.w;
      q2 += q4.x * q4.x + q4.y * q4.y + q4.z * q4.z + q4.w * q4.w;
    }
    xd *= dn;
    const float dg = 0.5f * dn * dn * q2;
    const size_t ridx = ((size_t)(b * H_ + h)) * S_ + s;
    KF[ridx * M_ + tid] = xd;
    if (tid == 0) DIAGK[ridx] = dg;
    bmax = fmaxf(bmax, xd);
    __syncthreads();
  }
  bmax = warp_max64(bmax);
  if ((tid & 63) == 0) red[tid >> 6] = bmax;
  __syncthreads();
  if (tid == 0) PMAX[bx] = fmaxf(fmaxf(red[0], red[1]), fmaxf(red[2], red[3]));
}

// ---------------- global max reduce ----------------
__global__ __launch_bounds__(256) void maxred_k(
    const float* __restrict__ PM, int n, float* __restrict__ G) {
  __shared__ float w[4];
  const int tid = threadIdx.x;
  float v = -3.0e38f;
  for (int i = tid; i < n; i += 256) v = fmaxf(v, PM[i]);
  v = warp_max64(v);
  if ((tid & 63) == 0) w[tid >> 6] = v;
  __syncthreads();
  if (tid == 0) G[0] = fmaxf(fmaxf(w[0], w[1]), fmaxf(w[2], w[3]));
}

// ---------------- key features: phase 2 ----------------
__global__ __launch_bounds__(256) void feat_k2_k(
    float* __restrict__ KF, const float* __restrict__ DIAG,
    const float* __restrict__ G) {
  const float gm = G[0];
  const size_t n = (size_t)B_ * H_ * S_ * M_;
  for (size_t i = (size_t)blockIdx.x * 256 + threadIdx.x; i < n;
       i += (size_t)gridDim.x * 256) {
    const float xd = KF[i];
    const float dg = DIAG[i >> 8];  // M_=256
    KF[i] = 0.0625f * (expf(xd - dg - gm) + 1e-4f);
  }
}

// ---------------- per-chunk k^T v sums ----------------
__global__ __launch_bounds__(256) void chunk_sums_k(
    const float* __restrict__ KF, const float* __restrict__ V,
    float* __restrict__ CSKV, float* __restrict__ CSZ) {
  __shared__ alignas(16) float vl[CH_ * DH_];  // 32 KB
  const int tid = threadIdx.x, blk = blockIdx.x;
  const int c = blk & 15, h = (blk >> 4) & 7, b = blk >> 7;
  const int bh = b * H_ + h;
#pragma unroll
  for (int i = 0; i < 32; i++) {
    const int e = i * 256 + tid;
    vl[e] = V[((size_t)(b * S_ + c * CH_ + (e >> 6))) * E_ + h * DH_ + (e & 63)];
  }
  __syncthreads();
  float4 acc[16];
#pragma unroll
  for (int i = 0; i < 16; i++) acc[i] = make_float4(0.f, 0.f, 0.f, 0.f);
  float z = 0.f;
  const size_t kfbase = ((size_t)bh * S_ + c * CH_) * M_ + tid;
  for (int t = 0; t < CH_; t++) {
    const float kf = KF[kfbase + (size_t)t * M_];
    z += kf;
#pragma unroll
    for (int i = 0; i < 16; i++) {
      const float4 vv = *reinterpret_cast<const float4*>(&vl[t * DH_ + i * 4]);
      acc[i].x += kf * vv.x; acc[i].y += kf * vv.y;
      acc[i].z += kf * vv.z; acc[i].w += kf * vv.w;
    }
  }
  const size_t base = ((size_t)bh * NC_ + c) * (M_ * DH_) + (size_t)tid * DH_;
#pragma unroll
  for (int i = 0; i < 16; i++)
    *reinterpret_cast<float4*>(&CSKV[base + i * 4]) = acc[i];
  CSZ[((size_t)bh * NC_ + c) * M_ + tid] = z;
}

// ---------------- exclusive prefix over chunks ----------------
__global__ __launch_bounds__(256) void chunk_prefix_k(
    float* __restrict__ CSKV, float* __restrict__ CSZ) {
  const int tid = threadIdx.x, bx = blockIdx.x;
  const int ds = bx & 15, bh = bx >> 4;
  float run[4] = {0.f, 0.f, 0.f, 0.f};
  for (int c = 0; c < NC_; c++) {
    const size_t base = ((size_t)bh * NC_ + c) * (M_ * DH_) + ds * 1024;
#pragma unroll
    for (int i = 0; i < 4; i++) {
      const size_t idx = base + i * 256 + tid;
      const float t = CSKV[idx];
      CSKV[idx] = run[i];
      run[i] += t;
    }
  }
  if (ds == 0) {
    float zr = 0.f;
    for (int c = 0; c < NC_; c++) {
      const size_t idx = ((size_t)bh * NC_ + c) * M_ + tid;
      const float t = CSZ[idx];
      CSZ[idx] = zr;
      zr += t;
    }
  }
}

// ---------------- in-chunk recurrence -> attention output (ext bf16) ----------------
__global__ __launch_bounds__(256) void attn_out_k(
    const float* __restrict__ QF, const float* __restrict__ KF,
    const float* __restrict__ V, const float* __restrict__ CSKV,
    const float* __restrict__ CSZ, u16* __restrict__ Oe) {
  constexpr int DSP = 32;
  __shared__ alignas(16) float Sl[M_ * 36];
  __shared__ alignas(16) float qrow[M_];
  __shared__ alignas(16) float vrow[DSP];
  __shared__ float np[256];
  __shared__ float denp[4];
  const int tid = threadIdx.x, blk = blockIdx.x;
  const int dh = blk & 1, c = (blk >> 1) & 15, h = (blk >> 5) & 7, b = blk >> 8;
  const int bh = b * H_ + h;
  const size_t sbase = ((size_t)bh * NC_ + c) * (M_ * DH_) + dh * DSP;
#pragma unroll
  for (int i = 0; i < 32; i++) {
    const int e = i * 256 + tid;  // 8192: m=e>>5, d=e&31
    Sl[(e >> 5) * 36 + (e & 31)] = CSKV[sbase + (size_t)(e >> 5) * DH_ + (e & 31)];
  }
  float zreg = CSZ[((size_t)bh * NC_ + c) * M_ + tid];
  const int wid = tid >> 6, lane = tid & 63;
  __syncthreads();
  const size_t qkbase = ((size_t)bh * S_ + c * CH_) * M_;
  for (int t = 0; t < CH_; t++) {
    const int sg = c * CH_ + t;
    if (tid < DSP) vrow[tid] = V[((size_t)(b * S_ + sg)) * E_ + h * DH_ + dh * DSP + tid];
    qrow[tid] = QF[qkbase + (size_t)t * M_ + tid];
    const float kft = KF[qkbase + (size_t)t * M_ + tid];
    __syncthreads();  // #1: staging done
    zreg += kft;
    float* srow = &Sl[tid * 36];
#pragma unroll
    for (int i = 0; i < 8; i++) {
      float4 sv = *reinterpret_cast<float4*>(&srow[i * 4]);
      const float4 vv = *reinterpret_cast<const float4*>(&vrow[i * 4]);
      sv.x += kft * vv.x; sv.y += kft * vv.y;
      sv.z += kft * vv.z; sv.w += kft * vv.w;
      *reinterpret_cast<float4*>(&srow[i * 4]) = sv;
    }
    const float dp = warp_sum64(qrow[tid] * zreg);
    if (lane == 0) denp[wid] = dp;
    __syncthreads();  // #2: state updated, denp written
    {
      const int g = tid >> 5, d = tid & 31;
      float p = 0.f;
#pragma unroll
      for (int mm = 0; mm < 32; mm++)
        p += qrow[g * 32 + mm] * Sl[(g * 32 + mm) * 36 + d];
      np[g * 32 + d] = p;
    }
    __syncthreads();  // #3: partials written
    if (tid < DSP) {
      float num = 0.f;
#pragma unroll
      for (int g = 0; g < 8; g++) num += np[g * 32 + tid];
      const float den = denp[0] + denp[1] + denp[2] + denp[3];
      const float ov = num / (den + 1e-6f);
      const int cb = h * DH_ + dh * DSP + tid;
      ext_write(Oe + (size_t)(b * S_ + sg) * KE_, cb, E_, ov);
    }
  }
}

// ---------------- host launch ----------------
extern "C" void kernel_launch(void* const* d_in, const int* in_sizes, int n_in,
                              void* d_out, int out_size, void* d_ws, size_t ws_size,
                              hipStream_t stream) {
  const int*   src      = (const int*)d_in[0];
  const float* emb      = (const float*)d_in[2];
  const float* ln_emb_g = (const float*)d_in[3];
  const float* ln_emb_b = (const float*)d_in[4];
  const float* Wq       = (const float*)d_in[5];
  const float* Wk       = (const float*)d_in[6];
  const float* Wv       = (const float*)d_in[7];
  const float* Wo       = (const float*)d_in[8];
  const float* ln1_g    = (const float*)d_in[9];
  const float* ln1_b    = (const float*)d_in[10];
  const float* W1       = (const float*)d_in[11];
  const float* b1       = (const float*)d_in[12];
  const float* W2       = (const float*)d_in[13];
  const float* b2       = (const float*)d_in[14];
  const float* ln2_g    = (const float*)d_in[15];
  const float* ln2_b    = (const float*)d_in[16];
  const float* proj     = (const float*)d_in[17];
  const float* fc_w     = (const float*)d_in[18];
  const float* fc_b     = (const float*)d_in[19];
  float* out = (float*)d_out;
  float* ws  = (float*)d_ws;

  size_t off = 0;
  auto alloc = [&](size_t n) {
    float* p = ws + off;
    off += (n + 63) & ~(size_t)63;
    return p;
  };
  float* X    = alloc((size_t)NTOK_ * E_);
  float* Qb   = alloc((size_t)NTOK_ * E_);
  float* Kb   = alloc((size_t)NTOK_ * E_);
  float* Vb   = alloc((size_t)NTOK_ * E_);
  float* QF   = alloc((size_t)B_ * H_ * S_ * M_);
  float* KF   = alloc((size_t)B_ * H_ * S_ * M_);
  float* CSKV = alloc((size_t)B_ * H_ * NC_ * M_ * DH_);
  float* CSZ  = alloc((size_t)B_ * H_ * NC_ * M_);
  float* DIAGK= alloc((size_t)B_ * H_ * S_);
  float* PMAX = alloc(4096);
  float* GMAX = alloc(64);
  // bf16 ext buffers (allocated in float units; 2 u16 per float)
  u16* Hext  = (u16*)alloc((size_t)NTOK_ * KE_ / 2);        // LN out / X ext
  u16* Oext  = (u16*)alloc((size_t)NTOK_ * KE_ / 2);        // attn out ext
  u16* Gext  = (u16*)alloc((size_t)NTOK_ * KF_ / 2);        // FFN mid ext / fc_w slab
  u16* WqkvoE= (u16*)alloc((size_t)4 * E_ * KE_ / 2);
  u16* W1E   = (u16*)alloc((size_t)(4 * E_) * KE_ / 2);
  u16* W2E   = (u16*)alloc((size_t)E_ * KF_ / 2);

  const dim3 blk256(256);
  const dim3 gQKV(E_ / 128, NTOK_ / 64);          // (4, 64)  BM=64
  const dim3 gFFN1(4 * E_ / 128, NTOK_ / 128);    // (16, 32) BM=128

  embed_ln_k<<<NTOK_, blk256, 0, stream>>>(src, emb, ln_emb_g, ln_emb_b, X);

  for (int l = 0; l < L_; l++) {
    const float* Pl = proj + (size_t)l * M_ * DH_;
    convw4_k<<<dim3(E_ / 32, E_ / 32, 4), blk256, 0, stream>>>(
        Wq + (size_t)l * E_ * E_, Wk + (size_t)l * E_ * E_,
        Wv + (size_t)l * E_ * E_, Wo + (size_t)l * E_ * E_, WqkvoE);
    ln_rows_ext_k<<<NTOK_, blk256, 0, stream>>>(X, ln1_g + l * E_, ln1_b + l * E_, Hext);
    gemm_bf3<64, false, false, false><<<gQKV, blk256, 0, stream>>>(
        Hext, WqkvoE + (size_t)0 * E_ * KE_, nullptr, Qb, nullptr, KE_, E_, 0);
    gemm_bf3<64, false, false, false><<<gQKV, blk256, 0, stream>>>(
        Hext, WqkvoE + (size_t)1 * E_ * KE_, nullptr, Kb, nullptr, KE_, E_, 0);
    gemm_bf3<64, false, false, false><<<gQKV, blk256, 0, stream>>>(
        Hext, WqkvoE + (size_t)2 * E_ * KE_, nullptr, Vb, nullptr, KE_, E_, 0);
    feat_q_k<<<B_ * H_ * (S_ / 8), blk256, 0, stream>>>(Qb, Pl, QF);
    feat_k1_k<<<B_ * H_ * (S_ / 8), blk256, 0, stream>>>(Kb, Pl, KF, DIAGK, PMAX);
    maxred_k<<<1, blk256, 0, stream>>>(PMAX, B_ * H_ * (S_ / 8), GMAX);
    feat_k2_k<<<4096, blk256, 0, stream>>>(KF, DIAGK, GMAX);
    chunk_sums_k<<<B_ * H_ * NC_, blk256, 0, stream>>>(KF, Vb, CSKV, CSZ);
    chunk_prefix_k<<<B_ * H_ * 16, blk256, 0, stream>>>(CSKV, CSZ);
    attn_out_k<<<B_ * H_ * NC_ * 2, blk256, 0, stream>>>(QF, KF, Vb, CSKV, CSZ, Oext);
    gemm_bf3<64, false, true, false><<<gQKV, blk256, 0, stream>>>(
        Oext, WqkvoE + (size_t)3 * E_ * KE_, nullptr, X, nullptr, KE_, E_, 0);
    ln_rows_ext_k<<<NTOK_, blk256, 0, stream>>>(X, ln2_g + l * E_, ln2_b + l * E_, Hext);
    convw_k<<<dim3(4 * E_ / 32, E_ / 32), blk256, 0, stream>>>(
        W1 + (size_t)l * E_ * 4 * E_, W1E, E_, 4 * E_);
    gemm_bf3<128, true, false, true><<<gFFN1, blk256, 0, stream>>>(
        Hext, W1E, b1 + (size_t)l * 4 * E_, nullptr, Gext, KE_, 0, 4 * E_);
    convw_k<<<dim3(E_ / 32, 4 * E_ / 32), blk256, 0, stream>>>(
        W2 + (size_t)l * 4 * E_ * E_, W2E, 4 * E_, E_);
    gemm_bf3<64, true, true, false><<<gQKV, blk256, 0, stream>>>(
        Gext, W2E, b2 + (size_t)l * E_, X, nullptr, KF_, E_, 0);
  }
  xconv_k<<<NTOK_, blk256, 0, stream>>>(X, Hext);
  // vocab GEMM in 2 slabs of 16000 columns, fc_w slab converted into Gext
  for (int sl = 0; sl < 2; sl++) {
    const int n0 = sl * 16000;
    convw_k<<<dim3(16000 / 32, E_ / 32), blk256, 0, stream>>>(
        fc_w + n0, Gext, E_, V_);
    gemm_bf3<128, true, false, false><<<dim3(16000 / 128, NTOK_ / 128), blk256, 0, stream>>>(
        Hext, Gext, fc_b + n0, out + n0, nullptr, KE_, V_, 0);
  }
}

// Round 3
// 3666.357 us; speedup vs baseline: 1.7763x; 1.1251x over previous
//
#include <hip/hip_runtime.h>
#include <math.h>

typedef unsigned short u16;
typedef unsigned int u32;
typedef __attribute__((ext_vector_type(8))) short bf16x8;
typedef __attribute__((ext_vector_type(4))) float f32x4;

// ---------------- problem constants ----------------
constexpr int B_  = 2;
constexpr int S_  = 2048;
constexpr int V_  = 32000;
constexpr int E_  = 512;
constexpr int H_  = 8;
constexpr int L_  = 4;
constexpr int DH_ = 64;     // E/H
constexpr int M_  = 256;    // FAVOR features
constexpr int CH_ = 128;    // chunk
constexpr int NC_ = 16;     // S/CH
constexpr int NTOK_ = B_ * S_;   // 4096
constexpr int KE_ = 3 * E_;      // 1536 extended-K for K=512
constexpr int KF_ = 3 * 4 * E_;  // 6144 extended-K for K=2048

// ---------------- helpers ----------------
__device__ __forceinline__ float warp_sum64(float x) {
#pragma unroll
  for (int off = 32; off; off >>= 1) x += __shfl_xor(x, off);
  return x;
}
__device__ __forceinline__ float warp_max64(float x) {
#pragma unroll
  for (int off = 32; off; off >>= 1) x = fmaxf(x, __shfl_xor(x, off));
  return x;
}
__device__ __forceinline__ u16 bf16_rne(float x) {
  u32 u = __builtin_bit_cast(u32, x);
  u += 0x7fffu + ((u >> 16) & 1u);
  return (u16)(u >> 16);
}
__device__ __forceinline__ float bf16_f(u16 h) {
  u32 u = ((u32)h) << 16;
  return __builtin_bit_cast(float, u);
}
__device__ __forceinline__ void gload_lds16(const u16* g, u16* l) {
  __builtin_amdgcn_global_load_lds(
      (const __attribute__((address_space(1))) void*)g,
      (__attribute__((address_space(3))) void*)l, 16, 0, 0);
}
// write one fp32 value as [hi | hi | lo] ext triplet at row base (stride seg)
__device__ __forceinline__ void ext_write(u16* ro, int col, int seg, float v) {
  const u16 hi = bf16_rne(v);
  const u16 lo = bf16_rne(v - bf16_f(hi));
  ro[col] = hi; ro[seg + col] = hi; ro[2 * seg + col] = lo;
}

// ---------------- embed + posenc + LN ----------------
__global__ __launch_bounds__(256) void embed_ln_k(
    const int* __restrict__ src, const float* __restrict__ emb,
    const float* __restrict__ g, const float* __restrict__ bta,
    float* __restrict__ X) {
  __shared__ float red[4];
  const int row = blockIdx.x;          // b*S + s
  const int s   = row & (S_ - 1);
  const int tid = threadIdx.x;
  const int tok = src[row];
  float v[2];
#pragma unroll
  for (int i = 0; i < 2; i++) {
    const int e = tid + i * 256;
    const float j = (float)(e & ~1);
    const float div = expf(j * (-9.210340371976184f / (float)E_)); // ln(1e4)
    const float ang = (float)s * div;
    const float pe = (e & 1) ? cosf(ang) : sinf(ang);
    v[i] = emb[(size_t)tok * E_ + e] + pe;
  }
  float sum = warp_sum64(v[0] + v[1]);
  if ((tid & 63) == 0) red[tid >> 6] = sum;
  __syncthreads();
  const float mu = (red[0] + red[1] + red[2] + red[3]) * (1.f / E_);
  __syncthreads();
  const float d0 = v[0] - mu, d1 = v[1] - mu;
  float s2 = warp_sum64(d0 * d0 + d1 * d1);
  if ((tid & 63) == 0) red[tid >> 6] = s2;
  __syncthreads();
  const float var = (red[0] + red[1] + red[2] + red[3]) * (1.f / E_);
  const float r = rsqrtf(var + 1e-5f);
  X[(size_t)row * E_ + tid]       = d0 * r * g[tid] + bta[tid];
  X[(size_t)row * E_ + tid + 256] = d1 * r * g[tid + 256] + bta[tid + 256];
}

// ---------------- row LayerNorm -> ext bf16 (GEMM-A format) ----------------
__global__ __launch_bounds__(256) void ln_rows_ext_k(
    const float* __restrict__ Xin, const float* __restrict__ g,
    const float* __restrict__ bta, u16* __restrict__ Eo) {
  __shared__ float red[4];
  const int row = blockIdx.x, tid = threadIdx.x;
  const float* xr = Xin + (size_t)row * E_;
  const float v0 = xr[tid], v1 = xr[tid + 256];
  float sum = warp_sum64(v0 + v1);
  if ((tid & 63) == 0) red[tid >> 6] = sum;
  __syncthreads();
  const float mu = (red[0] + red[1] + red[2] + red[3]) * (1.f / E_);
  __syncthreads();
  const float d0 = v0 - mu, d1 = v1 - mu;
  float s2 = warp_sum64(d0 * d0 + d1 * d1);
  if ((tid & 63) == 0) red[tid >> 6] = s2;
  __syncthreads();
  const float var = (red[0] + red[1] + red[2] + red[3]) * (1.f / E_);
  const float r = rsqrtf(var + 1e-5f);
  u16* ro = Eo + (size_t)row * KE_;
  ext_write(ro, tid,       E_, d0 * r * g[tid] + bta[tid]);
  ext_write(ro, tid + 256, E_, d1 * r * g[tid + 256] + bta[tid + 256]);
}

// ---------------- X fp32 -> ext bf16 ----------------
__global__ __launch_bounds__(256) void xconv_k(
    const float* __restrict__ X, u16* __restrict__ Eo) {
  const int row = blockIdx.x, tid = threadIdx.x;
  u16* ro = Eo + (size_t)row * KE_;
#pragma unroll
  for (int i = 0; i < 2; i++) {
    const int e = tid + i * 256;
    ext_write(ro, e, E_, X[(size_t)row * E_ + e]);
  }
}

// ---------------- weight convert: W[K][N] fp32 -> D[N][3K] bf16 [hi|lo|hi] ----------------
__global__ __launch_bounds__(256) void convw_k(
    const float* __restrict__ W, u16* __restrict__ D, int K, int ldsrc) {
  __shared__ float t[32][33];
  const int tid = threadIdx.x;
  const int n0 = blockIdx.x * 32, k0 = blockIdx.y * 32;
  const int r = tid >> 5, c = tid & 31;
#pragma unroll
  for (int i = 0; i < 4; i++)
    t[r + i * 8][c] = W[(size_t)(k0 + r + i * 8) * ldsrc + n0 + c];
  __syncthreads();
#pragma unroll
  for (int i = 0; i < 4; i++) {
    const int nn = r + i * 8;
    const float v = t[c][nn];
    const u16 hi = bf16_rne(v);
    const u16 lo = bf16_rne(v - bf16_f(hi));
    u16* ro = D + (size_t)(n0 + nn) * (3 * K) + k0 + c;
    ro[0] = hi; ro[K] = lo; ro[2 * K] = hi;
  }
}

// 4 square E x E weights at once (Q,K,V,O), selected by blockIdx.z
__global__ __launch_bounds__(256) void convw4_k(
    const float* __restrict__ p0, const float* __restrict__ p1,
    const float* __restrict__ p2, const float* __restrict__ p3,
    u16* __restrict__ D) {
  __shared__ float t[32][33];
  const int tid = threadIdx.x, z = blockIdx.z;
  const float* ps[4] = {p0, p1, p2, p3};
  const float* W = ps[z];
  u16* Dz = D + (size_t)z * E_ * KE_;
  const int n0 = blockIdx.x * 32, k0 = blockIdx.y * 32;
  const int r = tid >> 5, c = tid & 31;
#pragma unroll
  for (int i = 0; i < 4; i++)
    t[r + i * 8][c] = W[(size_t)(k0 + r + i * 8) * E_ + n0 + c];
  __syncthreads();
#pragma unroll
  for (int i = 0; i < 4; i++) {
    const int nn = r + i * 8;
    const float v = t[c][nn];
    const u16 hi = bf16_rne(v);
    const u16 lo = bf16_rne(v - bf16_f(hi));
    u16* ro = Dz + (size_t)(n0 + nn) * KE_ + k0 + c;
    ro[0] = hi; ro[E_] = lo; ro[2 * E_] = hi;
  }
}

// ---------------- bf16x3 MFMA GEMM ----------------
// C[M][N](f32) = A_ext[M][Kp](bf16) . Bt_ext[N][Kp](bf16)^T   (extended-K fp32 emulation)
// SWZ: panel-major block remap (8 col-blocks x all rows) for B-panel L2 residency.
template <int BM, bool BIAS, bool ACC, bool GEXT, bool SWZ>
__global__ __launch_bounds__(256) void gemm_bf3(
    const u16* __restrict__ A, const u16* __restrict__ Bt,
    const float* __restrict__ bias, float* __restrict__ C,
    u16* __restrict__ Eo, int Kp, int ldC, int NE) {
  constexpr int BN = 128, BK = 64;
  constexpr int WROWS = BM / 64;       // 2 or 1
  constexpr int WCOLS = 4 / WROWS;     // 2 or 4
  constexpr int CW = BN / WCOLS;       // 64 or 32
  constexpr int MR = 4;
  constexpr int NR = CW / 16;          // 4 or 2
  __shared__ u16 Al[BM * BK];
  __shared__ u16 Bl[BN * BK];
  const int tid = threadIdx.x;
  const int wid = tid >> 6, lane = tid & 63;
  const int wr = wid / WCOLS, wc = wid % WCOLS;
  const int l15 = lane & 15, l4 = lane >> 4;
  int bxi = blockIdx.x, byi = blockIdx.y;
  if constexpr (SWZ) {
    const int nbx = gridDim.x, nby = gridDim.y;
    const int lid = byi * nbx + bxi;
    const int nfull = nbx >> 3;
    const int pw = nby << 3;
    const int fullb = nfull * pw;
    if (lid < fullb) {
      const int pg = lid / pw;
      const int wi = lid - pg * pw;
      byi = wi >> 3;
      bxi = (pg << 3) + (wi & 7);
    } else {
      const int rem = lid - fullb;
      const int tcw = nbx - (nfull << 3);
      byi = rem / tcw;
      bxi = (nfull << 3) + rem - byi * tcw;
    }
  }
  const int bm = byi * BM, bn = bxi * BN;
  f32x4 acc[MR][NR];
#pragma unroll
  for (int i = 0; i < MR; i++)
#pragma unroll
    for (int j = 0; j < NR; j++) acc[i][j] = (f32x4)(0.f);
  const int srow = tid >> 3;          // 0..31
  const int scol = (tid & 7) * 8;     // 0..56
  const u16* Abase = A + (size_t)(bm + srow) * Kp + scol;
  const u16* Bbase = Bt + (size_t)(bn + srow) * Kp + scol;
  for (int k0 = 0; k0 < Kp; k0 += BK) {
#pragma unroll
    for (int i = 0; i < BM / 32; i++)
      gload_lds16(Abase + (size_t)(i * 32) * Kp + k0, Al + i * 2048 + tid * 8);
#pragma unroll
    for (int i = 0; i < 4; i++)
      gload_lds16(Bbase + (size_t)(i * 32) * Kp + k0, Bl + i * 2048 + tid * 8);
    __syncthreads();
#pragma unroll
    for (int kk = 0; kk < BK; kk += 32) {
      bf16x8 af[MR], bfr[NR];
#pragma unroll
      for (int i = 0; i < MR; i++)
        af[i] = *reinterpret_cast<const bf16x8*>(
            &Al[(wr * 64 + i * 16 + l15) * BK + kk + l4 * 8]);
#pragma unroll
      for (int j = 0; j < NR; j++)
        bfr[j] = *reinterpret_cast<const bf16x8*>(
            &Bl[(wc * CW + j * 16 + l15) * BK + kk + l4 * 8]);
#pragma unroll
      for (int i = 0; i < MR; i++)
#pragma unroll
        for (int j = 0; j < NR; j++)
          acc[i][j] = __builtin_amdgcn_mfma_f32_16x16x32_bf16(
              af[i], bfr[j], acc[i][j], 0, 0, 0);
    }
    __syncthreads();
  }
  // epilogue: C/D layout col=lane&15, row=(lane>>4)*4+reg
#pragma unroll
  for (int i = 0; i < MR; i++) {
#pragma unroll
    for (int j = 0; j < NR; j++) {
#pragma unroll
      for (int r = 0; r < 4; r++) {
        const int row = bm + wr * 64 + i * 16 + l4 * 4 + r;
        const int col = bn + wc * CW + j * 16 + l15;
        float v = acc[i][j][r];
        if constexpr (BIAS) v += bias[col];
        if constexpr (GEXT) {
          v = 0.5f * v * (1.f + erff(v * 0.7071067811865475f));
          ext_write(Eo + (size_t)row * (3 * NE), col, NE, v);
        } else {
          const size_t ci = (size_t)row * ldC + col;
          if constexpr (ACC) C[ci] += v; else C[ci] = v;
        }
      }
    }
  }
}

// ---------------- FAVOR+ query features ----------------
__global__ __launch_bounds__(256) void feat_q_k(
    const float* __restrict__ Q, const float* __restrict__ P,
    float* __restrict__ QF) {
  __shared__ alignas(16) float qrow[64];
  __shared__ float red[4];
  const int tid = threadIdx.x, bx = blockIdx.x;
  const int st = bx & 255, h = (bx >> 8) & 7, b = bx >> 11;
  float4 preg[16];
#pragma unroll
  for (int i = 0; i < 16; i++)
    preg[i] = *reinterpret_cast<const float4*>(&P[(size_t)tid * DH_ + i * 4]);
  const float dn = 0.35355339059327373f;  // 64^-0.25
  for (int ss = 0; ss < 8; ss++) {
    const int s = st * 8 + ss;
    if (tid < 64) qrow[tid] = Q[((size_t)(b * S_ + s)) * E_ + h * DH_ + tid];
    __syncthreads();
    float xd = 0.f, q2 = 0.f;
#pragma unroll
    for (int i = 0; i < 16; i++) {
      const float4 q4 = *reinterpret_cast<const float4*>(&qrow[i * 4]);
      xd += preg[i].x * q4.x + preg[i].y * q4.y + preg[i].z * q4.z + preg[i].w * q4.w;
      q2 += q4.x * q4.x + q4.y * q4.y + q4.z * q4.z + q4.w * q4.w;
    }
    xd *= dn;
    const float dg = 0.5f * dn * dn * q2;
    float mx = warp_max64(xd);
    if ((tid & 63) == 0) red[tid >> 6] = mx;
    __syncthreads();
    mx = fmaxf(fmaxf(red[0], red[1]), fmaxf(red[2], red[3]));
    QF[(((size_t)(b * H_ + h)) * S_ + s) * M_ + tid] =
        0.0625f * (expf(xd - dg - mx) + 1e-4f);
    __syncthreads();
  }
}

// ---------------- FAVOR+ key features: phase 1 ----------------
__global__ __launch_bounds__(256) void feat_k1_k(
    const float* __restrict__ K, const float* __restrict__ P,
    float* __restrict__ KF, float* __restrict__ DIAGK, float* __restrict__ PMAX) {
  __shared__ alignas(16) float krow[64];
  __shared__ float red[4];
  const int tid = threadIdx.x, bx = blockIdx.x;
  const int st = bx & 255, h = (bx >> 8) & 7, b = bx >> 11;
  float4 preg[16];
#pragma unroll
  for (int i = 0; i < 16; i++)
    preg[i] = *reinterpret_cast<const float4*>(&P[(size_t)tid * DH_ + i * 4]);
  const float dn = 0.35355339059327373f;
  float bmax = -3.0e38f;
  for (int ss = 0; ss < 8; ss++) {
    const int s = st * 8 + ss;
    if (tid < 64) krow[tid] = K[((size_t)(b * S_ + s)) * E_ + h * DH_ + tid];
    __syncthreads();
    float xd = 0.f, q2 = 0.f;
#pragma unroll
    for (int i = 0; i < 16; i++) {
      const float4 q4 = *reinterpret_cast<const float4*>(&krow[i * 4]);
      xd += preg[i].x * q4.x + preg[i].y * q4.y + preg[i].z * q4.z + preg[i].w * q4.w;
      q2 += q4.x * q4.x + q4.y * q4.y + q4.z * q4.z + q4.w * q4.w;
    }
    xd *= dn;
    const float dg = 0.5f * dn * dn * q2;
    const size_t ridx = ((size_t)(b * H_ + h)) * S_ + s;
    KF[ridx * M_ + tid] = xd;
    if (tid == 0) DIAGK[ridx] = dg;
    bmax = fmaxf(bmax, xd);
    __syncthreads();
  }
  bmax = warp_max64(bmax);
  if ((tid & 63) == 0) red[tid >> 6] = bmax;
  __syncthreads();
  if (tid == 0) PMAX[bx] = fmaxf(fmaxf(red[0], red[1]), fmaxf(red[2], red[3]));
}

// ---------------- global max reduce ----------------
__global__ __launch_bounds__(256) void maxred_k(
    const float* __restrict__ PM, int n, float* __restrict__ G) {
  __shared__ float w[4];
  const int tid = threadIdx.x;
  float v = -3.0e38f;
  for (int i = tid; i < n; i += 256) v = fmaxf(v, PM[i]);
  v = warp_max64(v);
  if ((tid & 63) == 0) w[tid >> 6] = v;
  __syncthreads();
  if (tid == 0) G[0] = fmaxf(fmaxf(w[0], w[1]), fmaxf(w[2], w[3]));
}

// ---------------- key features: phase 2 ----------------
__global__ __launch_bounds__(256) void feat_k2_k(
    float* __restrict__ KF, const float* __restrict__ DIAG,
    const float* __restrict__ G) {
  const float gm = G[0];
  const size_t n = (size_t)B_ * H_ * S_ * M_;
  for (size_t i = (size_t)blockIdx.x * 256 + threadIdx.x; i < n;
       i += (size_t)gridDim.x * 256) {
    const float xd = KF[i];
    const float dg = DIAG[i >> 8];  // M_=256
    KF[i] = 0.0625f * (expf(xd - dg - gm) + 1e-4f);
  }
}

// ---------------- per-chunk k^T v sums ----------------
__global__ __launch_bounds__(256) void chunk_sums_k(
    const float* __restrict__ KF, const float* __restrict__ V,
    float* __restrict__ CSKV, float* __restrict__ CSZ) {
  __shared__ alignas(16) float vl[CH_ * DH_];  // 32 KB
  const int tid = threadIdx.x, blk = blockIdx.x;
  const int c = blk & 15, h = (blk >> 4) & 7, b = blk >> 7;
  const int bh = b * H_ + h;
#pragma unroll
  for (int i = 0; i < 32; i++) {
    const int e = i * 256 + tid;
    vl[e] = V[((size_t)(b * S_ + c * CH_ + (e >> 6))) * E_ + h * DH_ + (e & 63)];
  }
  __syncthreads();
  float4 acc[16];
#pragma unroll
  for (int i = 0; i < 16; i++) acc[i] = make_float4(0.f, 0.f, 0.f, 0.f);
  float z = 0.f;
  const size_t kfbase = ((size_t)bh * S_ + c * CH_) * M_ + tid;
  for (int t = 0; t < CH_; t++) {
    const float kf = KF[kfbase + (size_t)t * M_];
    z += kf;
#pragma unroll
    for (int i = 0; i < 16; i++) {
      const float4 vv = *reinterpret_cast<const float4*>(&vl[t * DH_ + i * 4]);
      acc[i].x += kf * vv.x; acc[i].y += kf * vv.y;
      acc[i].z += kf * vv.z; acc[i].w += kf * vv.w;
    }
  }
  const size_t base = ((size_t)bh * NC_ + c) * (M_ * DH_) + (size_t)tid * DH_;
#pragma unroll
  for (int i = 0; i < 16; i++)
    *reinterpret_cast<float4*>(&CSKV[base + i * 4]) = acc[i];
  CSZ[((size_t)bh * NC_ + c) * M_ + tid] = z;
}

// ---------------- exclusive prefix over chunks ----------------
__global__ __launch_bounds__(256) void chunk_prefix_k(
    float* __restrict__ CSKV, float* __restrict__ CSZ) {
  const int tid = threadIdx.x, bx = blockIdx.x;
  const int ds = bx & 15, bh = bx >> 4;
  float run[4] = {0.f, 0.f, 0.f, 0.f};
  for (int c = 0; c < NC_; c++) {
    const size_t base = ((size_t)bh * NC_ + c) * (M_ * DH_) + ds * 1024;
#pragma unroll
    for (int i = 0; i < 4; i++) {
      const size_t idx = base + i * 256 + tid;
      const float t = CSKV[idx];
      CSKV[idx] = run[i];
      run[i] += t;
    }
  }
  if (ds == 0) {
    float zr = 0.f;
    for (int c = 0; c < NC_; c++) {
      const size_t idx = ((size_t)bh * NC_ + c) * M_ + tid;
      const float t = CSZ[idx];
      CSZ[idx] = zr;
      zr += t;
    }
  }
}

// ---------------- attention via per-chunk masked matmul ----------------
// One block per (b,h,chunk). A = QF KF^T (causal mask j<=i),
// num = A V + QF S_pre, den = rowsum(A) + QF z_pre. All fp32 VALU.
__global__ __launch_bounds__(256) void attn_mm_k(
    const float* __restrict__ QF, const float* __restrict__ KF,
    const float* __restrict__ V, const float* __restrict__ CSKV,
    const float* __restrict__ CSZ, u16* __restrict__ Oe) {
  constexpr int LDA = CH_ + 4;           // 132
  constexpr int KOFF = 64 * LDA;         // Ks offset inside QK
  constexpr int SSOFF = 64 * LDA;        // Ss offset inside QK (phase 2b)
  __shared__ alignas(16) float As[CH_ * LDA];       // A^T: As[j*LDA+i]
  __shared__ alignas(16) float QK[2 * 64 * LDA];    // Qs/Ks tiles; Vs; Qs+Ss
  __shared__ float zl[M_];
  __shared__ float den[CH_];
  __shared__ float denA[CH_ * 17];
  const int tid = threadIdx.x, blk = blockIdx.x;
  const int c = blk & 15, h = (blk >> 4) & 7, b = blk >> 7;
  const int bh = b * H_ + h;
  const int row0 = c * CH_;
  const size_t qkbase = ((size_t)bh * S_ + row0) * M_;
  const int tr = tid >> 4, tc = tid & 15;
  const int lr = tid >> 1, lq4 = (tid & 1) * 32;   // staging: row, float-offset
  zl[tid] = CSZ[((size_t)bh * NC_ + c) * M_ + tid];
  float acc[8][8];
#pragma unroll
  for (int i = 0; i < 8; i++)
#pragma unroll
    for (int j = 0; j < 8; j++) acc[i][j] = 0.f;
  float denq[8] = {0.f, 0.f, 0.f, 0.f, 0.f, 0.f, 0.f, 0.f};
  // ---- phase 1: A = QF KF^T over 4 m-tiles of 64 ----
  for (int mt = 0; mt < 4; mt++) {
    const float* qsrc = QF + qkbase + (size_t)lr * M_ + mt * 64 + lq4;
    const float* ksrc = KF + qkbase + (size_t)lr * M_ + mt * 64 + lq4;
#pragma unroll
    for (int u = 0; u < 8; u++) {
      const float4 q4 = *reinterpret_cast<const float4*>(qsrc + u * 4);
      const float4 k4 = *reinterpret_cast<const float4*>(ksrc + u * 4);
      const int m0 = lq4 + u * 4;
      QK[(m0 + 0) * LDA + lr] = q4.x; QK[(m0 + 1) * LDA + lr] = q4.y;
      QK[(m0 + 2) * LDA + lr] = q4.z; QK[(m0 + 3) * LDA + lr] = q4.w;
      QK[KOFF + (m0 + 0) * LDA + lr] = k4.x; QK[KOFF + (m0 + 1) * LDA + lr] = k4.y;
      QK[KOFF + (m0 + 2) * LDA + lr] = k4.z; QK[KOFF + (m0 + 3) * LDA + lr] = k4.w;
    }
    __syncthreads();
    // denq: this thread covers m = tc*4 .. +4 of this tile for its 8 rows
#pragma unroll
    for (int mm = 0; mm < 4; mm++) {
      const int m = tc * 4 + mm;
      const float zv = zl[mt * 64 + m];
      float a[8];
      *reinterpret_cast<float4*>(&a[0]) = *reinterpret_cast<const float4*>(&QK[m * LDA + tr * 8]);
      *reinterpret_cast<float4*>(&a[4]) = *reinterpret_cast<const float4*>(&QK[m * LDA + tr * 8 + 4]);
#pragma unroll
      for (int r = 0; r < 8; r++) denq[r] += a[r] * zv;
    }
#pragma unroll 8
    for (int mm = 0; mm < 64; mm++) {
      float a[8], bb[8];
      *reinterpret_cast<float4*>(&a[0]) = *reinterpret_cast<const float4*>(&QK[mm * LDA + tr * 8]);
      *reinterpret_cast<float4*>(&a[4]) = *reinterpret_cast<const float4*>(&QK[mm * LDA + tr * 8 + 4]);
      *reinterpret_cast<float4*>(&bb[0]) = *reinterpret_cast<const float4*>(&QK[KOFF + mm * LDA + tc * 8]);
      *reinterpret_cast<float4*>(&bb[4]) = *reinterpret_cast<const float4*>(&QK[KOFF + mm * LDA + tc * 8 + 4]);
#pragma unroll
      for (int i = 0; i < 8; i++)
#pragma unroll
        for (int j = 0; j < 8; j++) acc[i][j] += a[i] * bb[j];
    }
    __syncthreads();
  }
  // ---- mask + write A^T + row-sum partials ----
#pragma unroll
  for (int r = 0; r < 8; r++) {
    const int i = tr * 8 + r;
    float rs = denq[r];
#pragma unroll
    for (int jj = 0; jj < 8; jj++) {
      const int j = tc * 8 + jj;
      const float v = (j <= i) ? acc[r][jj] : 0.f;
      As[j * LDA + i] = v;
      rs += v;
    }
    denA[i * 17 + tc] = rs;
  }
  __syncthreads();
  if (tid < CH_) {
    float s = 0.f;
#pragma unroll
    for (int t = 0; t < 16; t++) s += denA[tid * 17 + t];
    den[tid] = s + 1e-6f;
  }
  // stage V into QK region: Vs[j*68+d]
  {
    const float* vsrc = V + ((size_t)(b * S_ + row0 + lr)) * E_ + h * DH_ + lq4;
#pragma unroll
    for (int u = 0; u < 8; u++) {
      const float4 v4 = *reinterpret_cast<const float4*>(vsrc + u * 4);
      *reinterpret_cast<float4*>(&QK[lr * 68 + lq4 + u * 4]) = v4;
    }
  }
  __syncthreads();
  // ---- phase 2a: num = A_masked V ----
  float num[8][4];
#pragma unroll
  for (int r = 0; r < 8; r++)
#pragma unroll
    for (int d = 0; d < 4; d++) num[r][d] = 0.f;
#pragma unroll 8
  for (int j = 0; j < CH_; j++) {
    float a[8];
    *reinterpret_cast<float4*>(&a[0]) = *reinterpret_cast<const float4*>(&As[j * LDA + tr * 8]);
    *reinterpret_cast<float4*>(&a[4]) = *reinterpret_cast<const float4*>(&As[j * LDA + tr * 8 + 4]);
    const float4 bv = *reinterpret_cast<const float4*>(&QK[j * 68 + tc * 4]);
#pragma unroll
    for (int r = 0; r < 8; r++) {
      num[r][0] += a[r] * bv.x; num[r][1] += a[r] * bv.y;
      num[r][2] += a[r] * bv.z; num[r][3] += a[r] * bv.w;
    }
  }
  __syncthreads();
  // ---- phase 2b: num += QF S_pre over 4 m-tiles ----
  const size_t sbase = ((size_t)bh * NC_ + c) * (M_ * DH_);
  for (int mt = 0; mt < 4; mt++) {
    const float* qsrc = QF + qkbase + (size_t)lr * M_ + mt * 64 + lq4;
#pragma unroll
    for (int u = 0; u < 8; u++) {
      const float4 q4 = *reinterpret_cast<const float4*>(qsrc + u * 4);
      const int m0 = lq4 + u * 4;
      QK[(m0 + 0) * LDA + lr] = q4.x; QK[(m0 + 1) * LDA + lr] = q4.y;
      QK[(m0 + 2) * LDA + lr] = q4.z; QK[(m0 + 3) * LDA + lr] = q4.w;
    }
    {
      const int lr2 = tid >> 2, lq2 = (tid & 3) * 16;
      const float* ssrc = CSKV + sbase + (size_t)(mt * 64 + lr2) * DH_ + lq2;
#pragma unroll
      for (int u = 0; u < 4; u++) {
        const float4 s4 = *reinterpret_cast<const float4*>(ssrc + u * 4);
        *reinterpret_cast<float4*>(&QK[SSOFF + lr2 * 68 + lq2 + u * 4]) = s4;
      }
    }
    __syncthreads();
#pragma unroll 8
    for (int mm = 0; mm < 64; mm++) {
      float a[8];
      *reinterpret_cast<float4*>(&a[0]) = *reinterpret_cast<const float4*>(&QK[mm * LDA + tr * 8]);
      *reinterpret_cast<float4*>(&a[4]) = *reinterpret_cast<const float4*>(&QK[mm * LDA + tr * 8 + 4]);
      const float4 sv = *reinterpret_cast<const float4*>(&QK[SSOFF + mm * 68 + tc * 4]);
#pragma unroll
      for (int r = 0; r < 8; r++) {
        num[r][0] += a[r] * sv.x; num[r][1] += a[r] * sv.y;
        num[r][2] += a[r] * sv.z; num[r][3] += a[r] * sv.w;
      }
    }
    __syncthreads();
  }
  // ---- epilogue: divide and ext-write ----
#pragma unroll
  for (int r = 0; r < 8; r++) {
    const int i = tr * 8 + r;
    const float dinv = 1.f / den[i];
    u16* ro = Oe + (size_t)(b * S_ + row0 + i) * KE_;
#pragma unroll
    for (int dd = 0; dd < 4; dd++) {
      const int d = tc * 4 + dd;
      ext_write(ro, h * DH_ + d, E_, num[r][dd] * dinv);
    }
  }
}

// ---------------- host launch ----------------
extern "C" void kernel_launch(void* const* d_in, const int* in_sizes, int n_in,
                              void* d_out, int out_size, void* d_ws, size_t ws_size,
                              hipStream_t stream) {
  const int*   src      = (const int*)d_in[0];
  const float* emb      = (const float*)d_in[2];
  const float* ln_emb_g = (const float*)d_in[3];
  const float* ln_emb_b = (const float*)d_in[4];
  const float* Wq       = (const float*)d_in[5];
  const float* Wk       = (const float*)d_in[6];
  const float* Wv       = (const float*)d_in[7];
  const float* Wo       = (const float*)d_in[8];
  const float* ln1_g    = (const float*)d_in[9];
  const float* ln1_b    = (const float*)d_in[10];
  const float* W1       = (const float*)d_in[11];
  const float* b1       = (const float*)d_in[12];
  const float* W2       = (const float*)d_in[13];
  const float* b2       = (const float*)d_in[14];
  const float* ln2_g    = (const float*)d_in[15];
  const float* ln2_b    = (const float*)d_in[16];
  const float* proj     = (const float*)d_in[17];
  const float* fc_w     = (const float*)d_in[18];
  const float* fc_b     = (const float*)d_in[19];
  float* out = (float*)d_out;
  float* ws  = (float*)d_ws;

  size_t off = 0;
  auto alloc = [&](size_t n) {
    float* p = ws + off;
    off += (n + 63) & ~(size_t)63;
    return p;
  };
  float* X    = alloc((size_t)NTOK_ * E_);
  float* Qb   = alloc((size_t)NTOK_ * E_);
  float* Kb   = alloc((size_t)NTOK_ * E_);
  float* Vb   = alloc((size_t)NTOK_ * E_);
  float* QF   = alloc((size_t)B_ * H_ * S_ * M_);
  float* KF   = alloc((size_t)B_ * H_ * S_ * M_);
  float* CSKV = alloc((size_t)B_ * H_ * NC_ * M_ * DH_);
  float* CSZ  = alloc((size_t)B_ * H_ * NC_ * M_);
  float* DIAGK= alloc((size_t)B_ * H_ * S_);
  float* PMAX = alloc(4096);
  float* GMAX = alloc(64);
  // bf16 ext buffers (allocated in float units; 2 u16 per float)
  u16* Hext  = (u16*)alloc((size_t)NTOK_ * KE_ / 2);        // LN out / X ext
  u16* Oext  = (u16*)alloc((size_t)NTOK_ * KE_ / 2);        // attn out ext
  u16* Gext  = (u16*)alloc((size_t)NTOK_ * KF_ / 2);        // FFN mid ext / fc_w slab
  u16* WqkvoE= (u16*)alloc((size_t)4 * E_ * KE_ / 2);
  u16* W1E   = (u16*)alloc((size_t)(4 * E_) * KE_ / 2);
  u16* W2E   = (u16*)alloc((size_t)E_ * KF_ / 2);

  const dim3 blk256(256);
  const dim3 gQKV(E_ / 128, NTOK_ / 64);          // (4, 64)  BM=64
  const dim3 gFFN1(4 * E_ / 128, NTOK_ / 128);    // (16, 32) BM=128

  embed_ln_k<<<NTOK_, blk256, 0, stream>>>(src, emb, ln_emb_g, ln_emb_b, X);

  for (int l = 0; l < L_; l++) {
    const float* Pl = proj + (size_t)l * M_ * DH_;
    convw4_k<<<dim3(E_ / 32, E_ / 32, 4), blk256, 0, stream>>>(
        Wq + (size_t)l * E_ * E_, Wk + (size_t)l * E_ * E_,
        Wv + (size_t)l * E_ * E_, Wo + (size_t)l * E_ * E_, WqkvoE);
    ln_rows_ext_k<<<NTOK_, blk256, 0, stream>>>(X, ln1_g + l * E_, ln1_b + l * E_, Hext);
    gemm_bf3<64, false, false, false, false><<<gQKV, blk256, 0, stream>>>(
        Hext, WqkvoE + (size_t)0 * E_ * KE_, nullptr, Qb, nullptr, KE_, E_, 0);
    gemm_bf3<64, false, false, false, false><<<gQKV, blk256, 0, stream>>>(
        Hext, WqkvoE + (size_t)1 * E_ * KE_, nullptr, Kb, nullptr, KE_, E_, 0);
    gemm_bf3<64, false, false, false, false><<<gQKV, blk256, 0, stream>>>(
        Hext, WqkvoE + (size_t)2 * E_ * KE_, nullptr, Vb, nullptr, KE_, E_, 0);
    feat_q_k<<<B_ * H_ * (S_ / 8), blk256, 0, stream>>>(Qb, Pl, QF);
    feat_k1_k<<<B_ * H_ * (S_ / 8), blk256, 0, stream>>>(Kb, Pl, KF, DIAGK, PMAX);
    maxred_k<<<1, blk256, 0, stream>>>(PMAX, B_ * H_ * (S_ / 8), GMAX);
    feat_k2_k<<<4096, blk256, 0, stream>>>(KF, DIAGK, GMAX);
    chunk_sums_k<<<B_ * H_ * NC_, blk256, 0, stream>>>(KF, Vb, CSKV, CSZ);
    chunk_prefix_k<<<B_ * H_ * 16, blk256, 0, stream>>>(CSKV, CSZ);
    attn_mm_k<<<B_ * H_ * NC_, blk256, 0, stream>>>(QF, KF, Vb, CSKV, CSZ, Oext);
    gemm_bf3<64, false, true, false, false><<<gQKV, blk256, 0, stream>>>(
        Oext, WqkvoE + (size_t)3 * E_ * KE_, nullptr, X, nullptr, KE_, E_, 0);
    ln_rows_ext_k<<<NTOK_, blk256, 0, stream>>>(X, ln2_g + l * E_, ln2_b + l * E_, Hext);
    convw_k<<<dim3(4 * E_ / 32, E_ / 32), blk256, 0, stream>>>(
        W1 + (size_t)l * E_ * 4 * E_, W1E, E_, 4 * E_);
    gemm_bf3<128, true, false, true, true><<<gFFN1, blk256, 0, stream>>>(
        Hext, W1E, b1 + (size_t)l * 4 * E_, nullptr, Gext, KE_, 0, 4 * E_);
    convw_k<<<dim3(E_ / 32, 4 * E_ / 32), blk256, 0, stream>>>(
        W2 + (size_t)l * 4 * E_ * E_, W2E, 4 * E_, E_);
    gemm_bf3<64, true, true, false, false><<<gQKV, blk256, 0, stream>>>(
        Gext, W2E, b2 + (size_t)l * E_, X, nullptr, KF_, E_, 0);
  }
  xconv_k<<<NTOK_, blk256, 0, stream>>>(X, Hext);
  // vocab GEMM in 2 slabs of 16000 columns, fc_w slab converted into Gext
  for (int sl = 0; sl < 2; sl++) {
    const int n0 = sl * 16000;
    convw_k<<<dim3(16000 / 32, E_ / 32), blk256, 0, stream>>>(
        fc_w + n0, Gext, E_, V_);
    gemm_bf3<128, true, false, false, true><<<dim3(16000 / 128, NTOK_ / 128), blk256, 0, stream>>>(
        Hext, Gext, fc_b + n0, out + n0, nullptr, KE_, V_, 0);
  }
}